// Round 8
// baseline (135.905 us; speedup 1.0000x reference)
//
#include <hip/hip_runtime.h>

#define NN 4096   // W*H
#define LOG2E 1.4426950408889634f
// layouts in d_ws:
//   Qg  [B][N][8] bf16 : g-projection (row i)
//   Kf  [B][N][8] bf16 : f-projection * log2e (row j)
//   V   [B][C][N] bf16 : h-projection
//   Lsp [B][N] u32     : packed {bf16 hi, bf16 lo} of  -log2(z_j)

typedef unsigned short u16;
typedef __attribute__((ext_vector_type(8))) short bf16x8;
typedef __attribute__((ext_vector_type(4))) float f32x4;

__device__ __forceinline__ u16 f2bf(float f){
  union { float f; unsigned u; } v; v.f = f;
  unsigned r = v.u + 0x7fffu + ((v.u >> 16) & 1u);   // RNE
  return (u16)(r >> 16);
}
__device__ __forceinline__ float bf2f(u16 h){
  union { unsigned u; float f; } v; v.u = ((unsigned)h) << 16;
  return v.f;
}

// ---------------- prep: 1x1 convs ---------------- (r7-verified, unchanged)
__global__ __launch_bounds__(256) void prep_kernel(
    const float* __restrict__ x,
    const float* __restrict__ Wf, const float* __restrict__ bfv,
    const float* __restrict__ Wg, const float* __restrict__ bgv,
    const float* __restrict__ Wh, const float* __restrict__ bhv,
    u16* __restrict__ Qg, u16* __restrict__ Kf, u16* __restrict__ V)
{
  __shared__ float xl[64][68];   // [pixel][channel]
  const int tid = threadIdx.x;
  const int lane = tid & 63, q = tid >> 6;   // q is wave-uniform
  const int b = blockIdx.x >> 6;
  const int i0 = (blockIdx.x & 63) << 6;
  const float* xb = x + ((size_t)b << 18);

  for (int r = 0; r < 16; ++r){
    int c = r * 4 + q;
    xl[lane][c] = xb[((size_t)c << 12) + i0 + lane];
  }
  __syncthreads();

  float xr[64];
#pragma unroll
  for (int c4 = 0; c4 < 16; ++c4){
    f32x4 v = *(const f32x4*)&xl[lane][c4 << 2];
    xr[c4*4+0]=v[0]; xr[c4*4+1]=v[1]; xr[c4*4+2]=v[2]; xr[c4*4+3]=v[3];
  }

  u16* vp = V + ((size_t)b << 18) + i0 + lane;
  for (int ch = 0; ch < 16; ++ch){
    int co = (q << 4) + ch;
    float acc = bhv[co];
    const float* wr = Wh + (co << 6);
#pragma unroll
    for (int c = 0; c < 64; ++c) acc = fmaf(wr[c], xr[c], acc);
    vp[(size_t)co << 12] = f2bf(acc);
  }
  {
    const int row = (b << 12) + i0 + lane;
    float a0 = bfv[2*q], a1 = bfv[2*q+1], c0 = bgv[2*q], c1 = bgv[2*q+1];
    const float* w0 = Wf + ((2*q) << 6); const float* w1 = Wf + ((2*q+1) << 6);
    const float* u0 = Wg + ((2*q) << 6); const float* u1 = Wg + ((2*q+1) << 6);
#pragma unroll
    for (int c = 0; c < 64; ++c){
      float xv = xr[c];
      a0 = fmaf(w0[c], xv, a0); a1 = fmaf(w1[c], xv, a1);
      c0 = fmaf(u0[c], xv, c0); c1 = fmaf(u1[c], xv, c1);
    }
    unsigned pf = f2bf(a0 * LOG2E) | ((unsigned)f2bf(a1 * LOG2E) << 16);
    unsigned pg = f2bf(c0) | ((unsigned)f2bf(c1) << 16);
    *(unsigned*)(Kf + (size_t)row * 8 + 2*q) = pf;
    *(unsigned*)(Qg + (size_t)row * 8 + 2*q) = pg;
  }
}

// ---------------- pass1 ---------------- (r7-verified, unchanged)
__global__ __launch_bounds__(256, 8) void pass1_kernel(
    const u16* __restrict__ Qg, const u16* __restrict__ Kf, unsigned* __restrict__ Lsp)
{
  __shared__ float zp[4][16];
  const int tid = threadIdx.x;
  const int w = tid >> 6, lane = tid & 63;
  const int l15 = lane & 15, g = lane >> 4;
  const int b = blockIdx.x >> 8;
  const int j0 = (blockIdx.x & 255) << 4;

  bf16x8 af = {0,0,0,0,0,0,0,0};
  if (lane < 16) af = *(const bf16x8*)(Kf + ((size_t)((b << 12) + j0 + lane)) * 8);

  const u16* qb = Qg + ((size_t)(b << 12)) * 8;
  float z0=0.f, z1=0.f, z2=0.f, z3=0.f;
  const f32x4 zero4 = {0.f,0.f,0.f,0.f};
  const int ibase = w << 10;
  for (int t = 0; t < 32; ++t){
    const int i = ibase + (t << 5);
    bf16x8 b0 = {0,0,0,0,0,0,0,0}, b1 = {0,0,0,0,0,0,0,0};
    if (lane < 16){
      b0 = *(const bf16x8*)(qb + (size_t)(i + lane) * 8);
      b1 = *(const bf16x8*)(qb + (size_t)(i + 16 + lane) * 8);
    }
    f32x4 s0 = __builtin_amdgcn_mfma_f32_16x16x32_bf16(af, b0, zero4, 0,0,0);
    f32x4 s1 = __builtin_amdgcn_mfma_f32_16x16x32_bf16(af, b1, zero4, 0,0,0);
    z0 += __builtin_amdgcn_exp2f(s0[0]) + __builtin_amdgcn_exp2f(s1[0]);
    z1 += __builtin_amdgcn_exp2f(s0[1]) + __builtin_amdgcn_exp2f(s1[1]);
    z2 += __builtin_amdgcn_exp2f(s0[2]) + __builtin_amdgcn_exp2f(s1[2]);
    z3 += __builtin_amdgcn_exp2f(s0[3]) + __builtin_amdgcn_exp2f(s1[3]);
  }
  float zz[4] = {z0,z1,z2,z3};
#pragma unroll
  for (int r = 0; r < 4; ++r){
#pragma unroll
    for (int off = 1; off < 16; off <<= 1)
      zz[r] += __shfl_xor(zz[r], off, 64);
  }
  if (l15 == 0){
#pragma unroll
    for (int r = 0; r < 4; ++r) zp[w][(g << 2) + r] = zz[r];
  }
  __syncthreads();
  if (tid < 16){
    float zs = zp[0][tid] + zp[1][tid] + zp[2][tid] + zp[3][tid];
    float nL = -__log2f(zs);
    u16 hi = f2bf(nL);
    u16 lo = f2bf(nL - bf2f(hi));
    Lsp[((size_t)b << 12) + j0 + tid] = (unsigned)hi | ((unsigned)lo << 16);
  }
}

// build PV B-operand fragment (r7-verified, unchanged)
__device__ __forceinline__ bf16x8 build_pb(const f32x4 sl, const f32x4 sh, int g, int l15){
  float e0 = __builtin_amdgcn_exp2f(sl[0]), e1 = __builtin_amdgcn_exp2f(sl[1]);
  float e2 = __builtin_amdgcn_exp2f(sl[2]), e3 = __builtin_amdgcn_exp2f(sl[3]);
  float h0 = __builtin_amdgcn_exp2f(sh[0]), h1 = __builtin_amdgcn_exp2f(sh[1]);
  float h2 = __builtin_amdgcn_exp2f(sh[2]), h3 = __builtin_amdgcn_exp2f(sh[3]);
  unsigned P0 = (unsigned)f2bf(e0) | ((unsigned)f2bf(e1) << 16);
  unsigned P1 = (unsigned)f2bf(e2) | ((unsigned)f2bf(e3) << 16);
  unsigned Q0 = (unsigned)f2bf(h0) | ((unsigned)f2bf(h1) << 16);
  unsigned Q1 = (unsigned)f2bf(h2) | ((unsigned)f2bf(h3) << 16);
  const int sA = (((g << 1) & 3) << 4) + l15;
  const int sB = ((((g << 1) + 1) & 3) << 4) + l15;
  int A0 = __shfl((int)P0, sA, 64), A1 = __shfl((int)P1, sA, 64);
  int A2 = __shfl((int)Q0, sA, 64), A3 = __shfl((int)Q1, sA, 64);
  int B0 = __shfl((int)P0, sB, 64), B1 = __shfl((int)P1, sB, 64);
  int B2 = __shfl((int)Q0, sB, 64), B3 = __shfl((int)Q1, sB, 64);
  const bool hi = (g >= 2);
  union { int d[4]; bf16x8 v; } u;
  u.d[0] = hi ? A2 : A0;   // {P[8g+0], P[8g+1]}
  u.d[1] = hi ? A3 : A1;   // {P[8g+2], P[8g+3]}
  u.d[2] = hi ? B2 : B0;   // {P[8g+4], P[8g+5]}
  u.d[3] = hi ? B3 : B1;   // {P[8g+6], P[8g+7]}
  return u.v;
}

// ---------------- pass2: O[c,i] = sum_j 2^{S2[j,i]-log2 z_j} * V[c,j]; out = gamma*O + x --------
// r7 datapath (verified) + 1-deep register software pipeline:
//   iter t: prefetch V(t+1), K(t+2); build P(t+1) [QK MFMA + exp + bpermute];
//           PV(t) on regs loaded/built last iter. VALU/DS of t+1 overlaps MFMA of t.
// + XCD-aware bijective block swizzle: each XCD's 128 contiguous blocks = one batch
//   -> its L2 holds exactly that batch's V (512 KB) + Kf (64 KB).
__global__ __launch_bounds__(256, 4) void pass2_kernel(
    const u16* __restrict__ Qg, const u16* __restrict__ Kf,
    const u16* __restrict__ V, const unsigned* __restrict__ Lsp,
    const float* __restrict__ x, const float* __restrict__ gammap,
    float* __restrict__ out)
{
  __shared__ __align__(16) float Of[2][32][68];   // 17.4 KB, epilogue only
  const int tid = threadIdx.x;
  const int w = tid >> 6, lane = tid & 63;        // w = jq
  const int l15 = lane & 15, g = lane >> 4;
  const int bid = blockIdx.x;
  const int swz = ((bid & 7) << 7) + (bid >> 3);  // bijective (1024 % 8 == 0)
  const int b = swz >> 7;
  const int i0b = (swz & 127) << 5;               // 32-row i-tile

  const u16* kb = Kf + ((size_t)(b << 12)) * 8;
  const u16* vb = V + ((size_t)b << 18);
  const unsigned* Lb = Lsp + ((size_t)b << 12);

  bf16x8 qf0 = {0,0,0,0,0,0,0,0}, qf1 = {0,0,0,0,0,0,0,0};
  if (lane < 16){
    qf0 = *(const bf16x8*)(Qg + ((size_t)((b << 12) + i0b + lane)) * 8);
    qf1 = *(const bf16x8*)(Qg + ((size_t)((b << 12) + i0b + 16 + lane)) * 8);
  } else if (lane < 32){
    ((unsigned*)&qf0)[0] = 0x3F803F80u;   // k=8,9 partners = 1.0,1.0
    ((unsigned*)&qf1)[0] = 0x3F803F80u;
  }

  f32x4 acc[2][4];
#pragma unroll
  for (int s = 0; s < 2; ++s)
#pragma unroll
    for (int ct = 0; ct < 4; ++ct) acc[s][ct] = (f32x4){0.f,0.f,0.f,0.f};

  const f32x4 zero4 = {0.f,0.f,0.f,0.f};
  const int jbase = w << 10;

  auto load_k = [&](int j0, bf16x8& kk0, bf16x8& kk1){
    kk0 = (bf16x8){0,0,0,0,0,0,0,0}; kk1 = (bf16x8){0,0,0,0,0,0,0,0};
    if (lane < 16){
      kk0 = *(const bf16x8*)(kb + (size_t)(j0 + lane) * 8);
      kk1 = *(const bf16x8*)(kb + (size_t)(j0 + 16 + lane) * 8);
    } else if (lane < 32){
      ((unsigned*)&kk0)[0] = Lb[j0 + l15];        // k=8,9: {-Lg_hi, -Lg_lo}
      ((unsigned*)&kk1)[0] = Lb[j0 + 16 + l15];
    }
  };
  auto load_v = [&](int j0, bf16x8& v0, bf16x8& v1, bf16x8& v2, bf16x8& v3){
    v0 = *(const bf16x8*)(vb + (((size_t)( 0 + l15)) << 12) + j0 + (g << 3));
    v1 = *(const bf16x8*)(vb + (((size_t)(16 + l15)) << 12) + j0 + (g << 3));
    v2 = *(const bf16x8*)(vb + (((size_t)(32 + l15)) << 12) + j0 + (g << 3));
    v3 = *(const bf16x8*)(vb + (((size_t)(48 + l15)) << 12) + j0 + (g << 3));
  };
  auto build_P = [&](const bf16x8 kk0, const bf16x8 kk1, bf16x8& p0, bf16x8& p1){
    f32x4 sl0 = __builtin_amdgcn_mfma_f32_16x16x32_bf16(kk0, qf0, zero4, 0,0,0);
    f32x4 sh0 = __builtin_amdgcn_mfma_f32_16x16x32_bf16(kk1, qf0, zero4, 0,0,0);
    f32x4 sl1 = __builtin_amdgcn_mfma_f32_16x16x32_bf16(kk0, qf1, zero4, 0,0,0);
    f32x4 sh1 = __builtin_amdgcn_mfma_f32_16x16x32_bf16(kk1, qf1, zero4, 0,0,0);
    p0 = build_pb(sl0, sh0, g, l15);
    p1 = build_pb(sl1, sh1, g, l15);
  };

  // pipeline state: vU=V(t), kU=K(t+1), pU=P(t)
  bf16x8 vU0,vU1,vU2,vU3, kU0,kU1, pU0,pU1;
  {
    bf16x8 k00,k01;
    load_k(jbase, k00, k01);
    load_v(jbase, vU0,vU1,vU2,vU3);
    build_P(k00, k01, pU0, pU1);       // P(0)
    load_k(jbase + 32, kU0, kU1);      // K(1)
  }

#pragma unroll 2
  for (int t = 0; t < 32; ++t){
    const int j0 = jbase + (t << 5);
    bf16x8 vN0,vN1,vN2,vN3, kN0,kN1, pN0,pN1;
    const bool h1 = (t + 1 < 32), h2 = (t + 2 < 32);
    if (h1) load_v(j0 + 32, vN0,vN1,vN2,vN3);       // V(t+1) in flight
    if (h2) load_k(j0 + 64, kN0, kN1);              // K(t+2) in flight
    if (h1) build_P(kU0, kU1, pN0, pN1);            // P(t+1): VALU/DS, overlaps PV(t) MFMAs
    // PV(t): O[c,i] += V(t) x P(t)
    __builtin_amdgcn_s_setprio(1);
    acc[0][0] = __builtin_amdgcn_mfma_f32_16x16x32_bf16(vU0, pU0, acc[0][0], 0,0,0);
    acc[0][1] = __builtin_amdgcn_mfma_f32_16x16x32_bf16(vU1, pU0, acc[0][1], 0,0,0);
    acc[0][2] = __builtin_amdgcn_mfma_f32_16x16x32_bf16(vU2, pU0, acc[0][2], 0,0,0);
    acc[0][3] = __builtin_amdgcn_mfma_f32_16x16x32_bf16(vU3, pU0, acc[0][3], 0,0,0);
    acc[1][0] = __builtin_amdgcn_mfma_f32_16x16x32_bf16(vU0, pU1, acc[1][0], 0,0,0);
    acc[1][1] = __builtin_amdgcn_mfma_f32_16x16x32_bf16(vU1, pU1, acc[1][1], 0,0,0);
    acc[1][2] = __builtin_amdgcn_mfma_f32_16x16x32_bf16(vU2, pU1, acc[1][2], 0,0,0);
    acc[1][3] = __builtin_amdgcn_mfma_f32_16x16x32_bf16(vU3, pU1, acc[1][3], 0,0,0);
    __builtin_amdgcn_s_setprio(0);
    if (h1){ vU0=vN0; vU1=vN1; vU2=vN2; vU3=vN3; pU0=pN0; pU1=pN1; }
    if (h2){ kU0=kN0; kU1=kN1; }
  }

  // epilogue (r7-verified, unchanged): two-phase partial combine through LDS
  if (w < 2){
#pragma unroll
    for (int s = 0; s < 2; ++s)
#pragma unroll
      for (int ct = 0; ct < 4; ++ct)
        *(f32x4*)&Of[w][(s << 4) + l15][(ct << 4) + (g << 2)] = acc[s][ct];
  }
  __syncthreads();
  if (w >= 2){
#pragma unroll
    for (int s = 0; s < 2; ++s)
#pragma unroll
      for (int ct = 0; ct < 4; ++ct){
        f32x4* p = (f32x4*)&Of[w - 2][(s << 4) + l15][(ct << 4) + (g << 2)];
        *p += acc[s][ct];
      }
  }
  __syncthreads();
  const float gamma = gammap[0];
  const int il = tid & 31, cg = tid >> 5;   // cg in [0,8)
#pragma unroll
  for (int cc = 0; cc < 8; ++cc){
    const int c = (cg << 3) + cc;
    const size_t idx = (((size_t)((b << 6) + c)) << 12) + i0b + il;
    const float o = Of[0][il][c] + Of[1][il][c];
    out[idx] = fmaf(gamma, o, x[idx]);
  }
}

extern "C" void kernel_launch(void* const* d_in, const int* in_sizes, int n_in,
                              void* d_out, int out_size, void* d_ws, size_t ws_size,
                              hipStream_t stream)
{
  (void)in_sizes; (void)n_in; (void)out_size; (void)ws_size;
  const float* x   = (const float*)d_in[0];
  const float* Wf  = (const float*)d_in[1];
  const float* bfv = (const float*)d_in[2];
  const float* Wg  = (const float*)d_in[3];
  const float* bgv = (const float*)d_in[4];
  const float* Wh  = (const float*)d_in[5];
  const float* bhv = (const float*)d_in[6];
  const float* gm  = (const float*)d_in[7];
  float* out = (float*)d_out;

  // workspace: Qg 512K | Kf 512K | V 4M | Lsp 128K  (= 5.125 MB)
  char* ws = (char*)d_ws;
  u16*  Qg = (u16*)(ws);
  u16*  Kf = (u16*)(ws + (1u << 19));
  u16*  Vv = (u16*)(ws + (1u << 20));
  unsigned* Lsp = (unsigned*)(ws + (1u << 20) + (1u << 22));

  prep_kernel<<<512, 256, 0, stream>>>(x, Wf, bfv, Wg, bgv, Wh, bhv, Qg, Kf, Vv);
  pass1_kernel<<<2048, 256, 0, stream>>>(Qg, Kf, Lsp);
  pass2_kernel<<<1024, 256, 0, stream>>>(Qg, Kf, Vv, Lsp, x, gm, out);
}